// Round 2
// baseline (473.203 us; speedup 1.0000x reference)
//
#include <hip/hip_runtime.h>

// Caps_Layer: x[1024,512,120] f32, W[120,25] f32 -> out[1024,5,5] f32
// Round 3 (resubmit; round-1 bench hit GPUAcquisitionTimeout, no data):
// transposed LDS K-tile (xt[k][row], odd row-stride 513) ->
//   - compute reads are lane-stride-1 b32 => conflict-free (was 8-way on b64:
//     52t mod 32 only covers 8 banks, gcd(52,32)=4 -- round-2 comment was wrong)
//   - KT 24->12 halves LDS to ~25KB => 5 blocks/CU (VGPR-capped), was 3 by LDS.
// Rows per thread: t and t+256 (routing is row-order agnostic).

#define NCAP 5
#define DCAP 5
#define NOUT 25      // NCAP*DCAP
#define DIN 120
#define SEQ 512
#define ROUTINGS 4

#define KT    12     // K-tile size (120 = 10*12)
#define LROW  513    // LDS row stride in floats (odd -> conflict-free lane-stride-1)

__global__ __launch_bounds__(256, 5) void caps_kernel(
    const float* __restrict__ x,   // [batch, 512, 120]
    const float* __restrict__ W,   // [120, 25]
    float* __restrict__ out)       // [batch, 5, 5]
{
    const int b    = blockIdx.x;
    const int t    = threadIdx.x;   // 0..255
    const int lane = t & 63;
    const int wv   = t >> 6;

    __shared__ float xt[KT * LROW];   // 12*513*4 = 24,624 B (transposed: [k][row])
    __shared__ float red[4][NOUT];

    const float* xb = x + (size_t)b * SEQ * DIN;

    float acc[2][NOUT];
#pragma unroll
    for (int r = 0; r < 2; ++r)
#pragma unroll
        for (int j = 0; j < NOUT; ++j) acc[r][j] = 0.f;

    // ---------- GEMM phase: 10 K-tiles of 12 ----------
    for (int tile = 0; tile < 10; ++tile) {
        const int k0 = tile * KT;

        // coalesced staging: 512 rows x 3 float4 = 1536 float4, 6/thread.
        // write transposed: xt[4q+j][row]; bank = (4q+j+row)%32 (513%32==1)
        // -> ~2 lanes/bank, near-conflict-free.
#pragma unroll
        for (int i = 0; i < 6; ++i) {
            int f   = t + 256 * i;
            int row = f / 3;
            int q   = f - row * 3;         // f % 3
            float4 v = *(const float4*)(xb + row * DIN + k0 + 4 * q);
            xt[(4 * q + 0) * LROW + row] = v.x;
            xt[(4 * q + 1) * LROW + row] = v.y;
            xt[(4 * q + 2) * LROW + row] = v.z;
            xt[(4 * q + 3) * LROW + row] = v.w;
        }
        __syncthreads();

        // compute from LDS: lane-stride-1 reads, conflict-free
#pragma unroll
        for (int k = 0; k < KT; ++k) {
            float a  = xt[k * LROW + t];          // row t
            float bv = xt[k * LROW + t + 256];    // row t+256
            const float* wr = W + (k0 + k) * NOUT;   // wave-uniform -> s_load
#pragma unroll
            for (int j = 0; j < NOUT; ++j) {
                float w = wr[j];
                acc[0][j] = fmaf(a,  w, acc[0][j]);
                acc[1][j] = fmaf(bv, w, acc[1][j]);
            }
        }
        __syncthreads();   // xt reused next tile
    }

    // ---------- Routing phase ----------
    float bb[2][NCAP];
#pragma unroll
    for (int r = 0; r < 2; ++r)
#pragma unroll
        for (int c = 0; c < NCAP; ++c) bb[r][c] = 0.f;

    float o[NOUT];

    for (int it = 0; it < ROUTINGS; ++it) {
        float p[NOUT];
#pragma unroll
        for (int j = 0; j < NOUT; ++j) p[j] = 0.f;

#pragma unroll
        for (int r = 0; r < 2; ++r) {
            float m = bb[r][0];
#pragma unroll
            for (int c = 1; c < NCAP; ++c) m = fmaxf(m, bb[r][c]);
            float e[NCAP]; float se = 0.f;
#pragma unroll
            for (int c = 0; c < NCAP; ++c) { e[c] = __expf(bb[r][c] - m); se += e[c]; }
            float inv = 1.f / se;
#pragma unroll
            for (int c = 0; c < NCAP; ++c) {
                float cc = e[c] * inv;
#pragma unroll
                for (int k = 0; k < DCAP; ++k)
                    p[c*DCAP + k] = fmaf(cc, acc[r][c*DCAP + k], p[c*DCAP + k]);
            }
        }

        // block reduction: 64-lane butterfly, then 4 waves via LDS
#pragma unroll
        for (int d = 1; d < 64; d <<= 1)
#pragma unroll
            for (int j = 0; j < NOUT; ++j) p[j] += __shfl_xor(p[j], d, 64);

        if (lane == 0) {
#pragma unroll
            for (int j = 0; j < NOUT; ++j) red[wv][j] = p[j];
        }
        __syncthreads();
        float s[NOUT];
#pragma unroll
        for (int j = 0; j < NOUT; ++j)
            s[j] = red[0][j] + red[1][j] + red[2][j] + red[3][j];
        __syncthreads();

        // squash per capsule
#pragma unroll
        for (int c = 0; c < NCAP; ++c) {
            float ss = 0.f;
#pragma unroll
            for (int k = 0; k < DCAP; ++k)
                ss = fmaf(s[c*DCAP + k], s[c*DCAP + k], ss);
            float sc = rsqrtf(ss + 1e-7f);
#pragma unroll
            for (int k = 0; k < DCAP; ++k) o[c*DCAP + k] = s[c*DCAP + k] * sc;
        }

        if (it < ROUTINGS - 1) {
#pragma unroll
            for (int r = 0; r < 2; ++r)
#pragma unroll
                for (int c = 0; c < NCAP; ++c) {
                    float d0 = 0.f;
#pragma unroll
                    for (int k = 0; k < DCAP; ++k)
                        d0 = fmaf(o[c*DCAP + k], acc[r][c*DCAP + k], d0);
                    bb[r][c] = d0;
                }
        }
    }

    if (t < NOUT) out[(size_t)b * NOUT + t] = o[t];
}

extern "C" void kernel_launch(void* const* d_in, const int* in_sizes, int n_in,
                              void* d_out, int out_size, void* d_ws, size_t ws_size,
                              hipStream_t stream) {
    const float* x   = (const float*)d_in[0];
    const float* W   = (const float*)d_in[1];
    float*       o   = (float*)d_out;
    const int batch  = in_sizes[0] / (SEQ * DIN);   // 1024
    caps_kernel<<<dim3(batch), dim3(256), 0, stream>>>(x, W, o);
}

// Round 3
// 407.555 us; speedup vs baseline: 1.1611x; 1.1611x over previous
//
#include <hip/hip_runtime.h>

// Caps_Layer: x[1024,512,120] f32, W[120,25] f32 -> out[1024,5,5] f32
// Round 4: keep round-3's transposed 25KB LDS tile (conflict-free compute
// reads, 6-blocks/CU-capable LDS) but DROP the __launch_bounds__(256,5)
// min-waves hint: it forced VGPR 92->48 and the routing phase (~90 live
// floats) spilled to scratch -- rocprof showed WRITE_SIZE 0.13->182MB and
// FETCH 234->562MB (spill round-trips), dur 170->236us. Plain (256) lets
// the allocator pick ~92 VGPR => 5 waves/EU, no spill, ~62% occupancy.

#define NCAP 5
#define DCAP 5
#define NOUT 25      // NCAP*DCAP
#define DIN 120
#define SEQ 512
#define ROUTINGS 4

#define KT    12     // K-tile size (120 = 10*12)
#define LROW  513    // LDS row stride in floats (odd -> conflict-free lane-stride-1)

__global__ __launch_bounds__(256) void caps_kernel(
    const float* __restrict__ x,   // [batch, 512, 120]
    const float* __restrict__ W,   // [120, 25]
    float* __restrict__ out)       // [batch, 5, 5]
{
    const int b    = blockIdx.x;
    const int t    = threadIdx.x;   // 0..255
    const int lane = t & 63;
    const int wv   = t >> 6;

    __shared__ float xt[KT * LROW];   // 12*513*4 = 24,624 B (transposed: [k][row])
    __shared__ float red[4][NOUT];

    const float* xb = x + (size_t)b * SEQ * DIN;

    float acc[2][NOUT];
#pragma unroll
    for (int r = 0; r < 2; ++r)
#pragma unroll
        for (int j = 0; j < NOUT; ++j) acc[r][j] = 0.f;

    // ---------- GEMM phase: 10 K-tiles of 12 ----------
    for (int tile = 0; tile < 10; ++tile) {
        const int k0 = tile * KT;

        // coalesced staging: 512 rows x 3 float4 = 1536 float4, 6/thread.
        // write transposed: xt[4q+j][row]; bank = (4q+j+row)%32 (513%32==1)
        // -> <=3 lanes/bank, near-free (~2-3% of block cycles per rocprof).
#pragma unroll
        for (int i = 0; i < 6; ++i) {
            int f   = t + 256 * i;
            int row = f / 3;
            int q   = f - row * 3;         // f % 3
            float4 v = *(const float4*)(xb + row * DIN + k0 + 4 * q);
            xt[(4 * q + 0) * LROW + row] = v.x;
            xt[(4 * q + 1) * LROW + row] = v.y;
            xt[(4 * q + 2) * LROW + row] = v.z;
            xt[(4 * q + 3) * LROW + row] = v.w;
        }
        __syncthreads();

        // compute from LDS: lane-stride-1 reads, conflict-free
#pragma unroll
        for (int k = 0; k < KT; ++k) {
            float a  = xt[k * LROW + t];          // row t
            float bv = xt[k * LROW + t + 256];    // row t+256
            const float* wr = W + (k0 + k) * NOUT;   // wave-uniform -> s_load
#pragma unroll
            for (int j = 0; j < NOUT; ++j) {
                float w = wr[j];
                acc[0][j] = fmaf(a,  w, acc[0][j]);
                acc[1][j] = fmaf(bv, w, acc[1][j]);
            }
        }
        __syncthreads();   // xt reused next tile
    }

    // ---------- Routing phase ----------
    float bb[2][NCAP];
#pragma unroll
    for (int r = 0; r < 2; ++r)
#pragma unroll
        for (int c = 0; c < NCAP; ++c) bb[r][c] = 0.f;

    float o[NOUT];

    for (int it = 0; it < ROUTINGS; ++it) {
        float p[NOUT];
#pragma unroll
        for (int j = 0; j < NOUT; ++j) p[j] = 0.f;

#pragma unroll
        for (int r = 0; r < 2; ++r) {
            float m = bb[r][0];
#pragma unroll
            for (int c = 1; c < NCAP; ++c) m = fmaxf(m, bb[r][c]);
            float e[NCAP]; float se = 0.f;
#pragma unroll
            for (int c = 0; c < NCAP; ++c) { e[c] = __expf(bb[r][c] - m); se += e[c]; }
            float inv = 1.f / se;
#pragma unroll
            for (int c = 0; c < NCAP; ++c) {
                float cc = e[c] * inv;
#pragma unroll
                for (int k = 0; k < DCAP; ++k)
                    p[c*DCAP + k] = fmaf(cc, acc[r][c*DCAP + k], p[c*DCAP + k]);
            }
        }

        // block reduction: 64-lane butterfly, then 4 waves via LDS
#pragma unroll
        for (int d = 1; d < 64; d <<= 1)
#pragma unroll
            for (int j = 0; j < NOUT; ++j) p[j] += __shfl_xor(p[j], d, 64);

        if (lane == 0) {
#pragma unroll
            for (int j = 0; j < NOUT; ++j) red[wv][j] = p[j];
        }
        __syncthreads();
        float s[NOUT];
#pragma unroll
        for (int j = 0; j < NOUT; ++j)
            s[j] = red[0][j] + red[1][j] + red[2][j] + red[3][j];
        __syncthreads();

        // squash per capsule
#pragma unroll
        for (int c = 0; c < NCAP; ++c) {
            float ss = 0.f;
#pragma unroll
            for (int k = 0; k < DCAP; ++k)
                ss = fmaf(s[c*DCAP + k], s[c*DCAP + k], ss);
            float sc = rsqrtf(ss + 1e-7f);
#pragma unroll
            for (int k = 0; k < DCAP; ++k) o[c*DCAP + k] = s[c*DCAP + k] * sc;
        }

        if (it < ROUTINGS - 1) {
#pragma unroll
            for (int r = 0; r < 2; ++r)
#pragma unroll
                for (int c = 0; c < NCAP; ++c) {
                    float d0 = 0.f;
#pragma unroll
                    for (int k = 0; k < DCAP; ++k)
                        d0 = fmaf(o[c*DCAP + k], acc[r][c*DCAP + k], d0);
                    bb[r][c] = d0;
                }
        }
    }

    if (t < NOUT) out[(size_t)b * NOUT + t] = o[t];
}

extern "C" void kernel_launch(void* const* d_in, const int* in_sizes, int n_in,
                              void* d_out, int out_size, void* d_ws, size_t ws_size,
                              hipStream_t stream) {
    const float* x   = (const float*)d_in[0];
    const float* W   = (const float*)d_in[1];
    float*       o   = (float*)d_out;
    const int batch  = in_sizes[0] / (SEQ * DIN);   // 1024
    caps_kernel<<<dim3(batch), dim3(256), 0, stream>>>(x, W, o);
}

// Round 4
// 404.151 us; speedup vs baseline: 1.1709x; 1.0084x over previous
//
#include <hip/hip_runtime.h>

// Caps_Layer: x[1024,512,120] f32, W[120,25] f32 -> out[1024,5,5] f32
// Round 5: async double-buffered GEMM staging via global_load_lds.
//  - LDS layout goes back to LINEAR [row][12] floats (no pad/transpose):
//    ds_read_b128 at byte 48t+16q has bank-starts 12t%32 covering all 8
//    4-bank groups per 8 lanes -> conflict-free (round-0's conflict came
//    from the pad-26 addressing, not row-major itself). KT=12 (stride 48B)
//    is the unique conflict-free choice (KT=8/24 give 2-way on b128).
//  - This f-ordered layout is exactly what global_load_lds produces
//    (wave-uniform LDS base + lane*16; per-lane global gather in 48B runs),
//    so staging needs no VGPR round-trip and NO ds_writes at all.
//  - Double buffer 2x24KB: per tile {issue async loads for tile+1 ->
//    compute tile -> __syncthreads (implicit vmcnt(0) drains loads that
//    overlapped the ~1200cyc FMA phase)}. 11 barriers vs 20; HBM latency
//    hidden under compute (catalog T3 minimum 2-phase template).
//  - Lesson kept from round 3: NO min-waves launch-bounds hint (forced
//    VGPR 92->48 and spilled 360MB of scratch traffic).

#define NCAP 5
#define DCAP 5
#define NOUT 25      // NCAP*DCAP
#define DIN 120
#define SEQ 512
#define ROUTINGS 4

#define KT    12     // K-tile size (120 = 10*12); stride 48B -> b128 conflict-free
#define NTILE 10
#define BUFF  (SEQ * KT)   // 6144 floats = 24,576 B per buffer

typedef __attribute__((address_space(3))) void        as3_void;
typedef const __attribute__((address_space(1))) void  as1_void;

__global__ __launch_bounds__(256) void caps_kernel(
    const float* __restrict__ x,   // [batch, 512, 120]
    const float* __restrict__ W,   // [120, 25]
    float* __restrict__ out)       // [batch, 5, 5]
{
    const int b    = blockIdx.x;
    const int t    = threadIdx.x;   // 0..255
    const int lane = t & 63;
    const int wv   = t >> 6;

    __shared__ float xt[2][BUFF];   // 49,152 B double buffer, linear [row][12]
    __shared__ float red[4][NOUT];

    const float* xb = x + (size_t)b * SEQ * DIN;

    float acc[2][NOUT];
#pragma unroll
    for (int r = 0; r < 2; ++r)
#pragma unroll
        for (int j = 0; j < NOUT; ++j) acc[r][j] = 0.f;

    // async stage of one K-tile: 1536 float4 chunks, 6/thread.
    // LDS slot f = t + 256*i  <->  global (row = f/3, quad = f%3):
    // lanes cover 48B-contiguous runs per row (coalesced), LDS dest is
    // wave-uniform base (HW adds lane*16).
    auto stage = [&](int bufi, int tile) {
        const int k0 = tile * KT;
#pragma unroll
        for (int i = 0; i < 6; ++i) {
            unsigned f   = (unsigned)t + 256u * (unsigned)i;
            unsigned row = f / 3u;
            unsigned q   = f - row * 3u;
            const float* gsrc = xb + row * DIN + k0 + 4u * q;
            float*      ldst = &xt[bufi][1024 * i + 256 * wv];   // wave-uniform
            __builtin_amdgcn_global_load_lds((as1_void*)gsrc, (as3_void*)ldst,
                                             16, 0, 0);
        }
    };

    // ---------- GEMM phase: software-pipelined 10 K-tiles ----------
    stage(0, 0);
    __syncthreads();                 // implicit vmcnt(0): tile 0 resident

    for (int tile = 0; tile < NTILE; ++tile) {
        const int cur = tile & 1;
        if (tile + 1 < NTILE) stage(cur ^ 1, tile + 1);   // issue EARLY

        const int k0 = tile * KT;
        const float* r0 = &xt[cur][t * KT];
        const float* r1 = &xt[cur][(t + 256) * KT];
#pragma unroll
        for (int q = 0; q < 3; ++q) {
            float4 a  = *(const float4*)(r0 + 4 * q);     // ds_read_b128
            float4 bv = *(const float4*)(r1 + 4 * q);
            const float* wr = W + (k0 + 4 * q) * NOUT;    // wave-uniform -> s_load
#pragma unroll
            for (int j = 0; j < NOUT; ++j) {
                float w0 = wr[j];
                float w1 = wr[j + NOUT];
                float w2 = wr[j + 2 * NOUT];
                float w3 = wr[j + 3 * NOUT];
                acc[0][j] = fmaf(a.w,  w3, fmaf(a.z,  w2, fmaf(a.y,  w1, fmaf(a.x,  w0, acc[0][j]))));
                acc[1][j] = fmaf(bv.w, w3, fmaf(bv.z, w2, fmaf(bv.y, w1, fmaf(bv.x, w0, acc[1][j]))));
            }
        }
        __syncthreads();   // drains next-tile loads + guards buffer reuse
    }

    // ---------- Routing phase ----------
    float bb[2][NCAP];
#pragma unroll
    for (int r = 0; r < 2; ++r)
#pragma unroll
        for (int c = 0; c < NCAP; ++c) bb[r][c] = 0.f;

    float o[NOUT];

    for (int it = 0; it < ROUTINGS; ++it) {
        float p[NOUT];
#pragma unroll
        for (int j = 0; j < NOUT; ++j) p[j] = 0.f;

#pragma unroll
        for (int r = 0; r < 2; ++r) {
            float m = bb[r][0];
#pragma unroll
            for (int c = 1; c < NCAP; ++c) m = fmaxf(m, bb[r][c]);
            float e[NCAP]; float se = 0.f;
#pragma unroll
            for (int c = 0; c < NCAP; ++c) { e[c] = __expf(bb[r][c] - m); se += e[c]; }
            float inv = 1.f / se;
#pragma unroll
            for (int c = 0; c < NCAP; ++c) {
                float cc = e[c] * inv;
#pragma unroll
                for (int k = 0; k < DCAP; ++k)
                    p[c*DCAP + k] = fmaf(cc, acc[r][c*DCAP + k], p[c*DCAP + k]);
            }
        }

        // block reduction: 64-lane butterfly, then 4 waves via LDS
#pragma unroll
        for (int d = 1; d < 64; d <<= 1)
#pragma unroll
            for (int j = 0; j < NOUT; ++j) p[j] += __shfl_xor(p[j], d, 64);

        if (lane == 0) {
#pragma unroll
            for (int j = 0; j < NOUT; ++j) red[wv][j] = p[j];
        }
        __syncthreads();
        float s[NOUT];
#pragma unroll
        for (int j = 0; j < NOUT; ++j)
            s[j] = red[0][j] + red[1][j] + red[2][j] + red[3][j];
        __syncthreads();

        // squash per capsule
#pragma unroll
        for (int c = 0; c < NCAP; ++c) {
            float ss = 0.f;
#pragma unroll
            for (int k = 0; k < DCAP; ++k)
                ss = fmaf(s[c*DCAP + k], s[c*DCAP + k], ss);
            float sc = rsqrtf(ss + 1e-7f);
#pragma unroll
            for (int k = 0; k < DCAP; ++k) o[c*DCAP + k] = s[c*DCAP + k] * sc;
        }

        if (it < ROUTINGS - 1) {
#pragma unroll
            for (int r = 0; r < 2; ++r)
#pragma unroll
                for (int c = 0; c < NCAP; ++c) {
                    float d0 = 0.f;
#pragma unroll
                    for (int k = 0; k < DCAP; ++k)
                        d0 = fmaf(o[c*DCAP + k], acc[r][c*DCAP + k], d0);
                    bb[r][c] = d0;
                }
        }
    }

    if (t < NOUT) out[(size_t)b * NOUT + t] = o[t];
}

extern "C" void kernel_launch(void* const* d_in, const int* in_sizes, int n_in,
                              void* d_out, int out_size, void* d_ws, size_t ws_size,
                              hipStream_t stream) {
    const float* x   = (const float*)d_in[0];
    const float* W   = (const float*)d_in[1];
    float*       o   = (float*)d_out;
    const int batch  = in_sizes[0] / (SEQ * DIN);   // 1024
    caps_kernel<<<dim3(batch), dim3(256), 0, stream>>>(x, W, o);
}